// Round 9
// baseline (554.445 us; speedup 1.0000x reference)
//
#include <hip/hip_runtime.h>

#define TSTEPS 512   // LSTM sequence length (2048/4)
#define HID    64

typedef float f2 __attribute__((ext_vector_type(2)));

__device__ __forceinline__ float sigm(float x) {
  return 1.0f / (1.0f + __expf(-x));
}
__device__ __forceinline__ float tanhf_(float x) {
  // tanh(x) = 1 - 2/(exp(2x)+1); exact at +-inf, fine vs 5e-3 threshold
  return 1.0f - 2.0f / (1.0f + __expf(2.0f * x));
}

// DPP lane-exchange add (VALU-only, no LDS pipe)
// 0xB1 = quad_perm xor1, 0x4E = quad_perm xor2, 0x141 = row_half_mirror (xor7)
#define DPP_ADD(x, ctrl)                                                       \
  x += __int_as_float(                                                         \
      __builtin_amdgcn_mov_dpp(__float_as_int(x), (ctrl), 0xf, 0xf, true))

// packed fp32 fma -> v_pk_fma_f32 on gfx950
#define PKFMA(acc, w, v) acc = __builtin_elementwise_fma((w), (v), (acc))

// gate-j dot fragments
#define DOT2(S, W, J, V0, V1)                                                  \
  PKFMA(S, W[2 * (J)], V0); PKFMA(S, W[2 * (J) + 1], V1);
#define DOT4(S, W, J, V0, V1, V2, V3)                                          \
  PKFMA(S, W[4 * (J)], V0);     PKFMA(S, W[4 * (J) + 1], V1);                  \
  PKFMA(S, W[4 * (J) + 2], V2); PKFMA(S, W[4 * (J) + 3], V3);

// load a float4 from real memory (global/LDS) and split into two f2
__device__ __forceinline__ void ld4(const float4* p, f2& a, f2& b) {
  const float4 t = *p;
  a = (f2){t.x, t.y};
  b = (f2){t.z, t.w};
}

// ---------------------------------------------------------------------------
// ONE kernel: conv1+pool -> t1 (global, L2-resident), conv2+pool -> featB
// (LDS-resident), 2-layer pipelined LSTM recurrence + fc.
// One block per batch element: 256 blocks x 512 threads (1 block/CU).
//
// v9: 8-lane/2-unit split to HALVE per-iter LDS-pipe traffic (the measured
// bottleneck: 112 ds_read_b128/iter x ~12cy = ~1350cy of the ~2100cy/iter).
//   group g = lt>>3 owns units {2g, 2g+1}; lane o = lt&7 covers dim-octant o
//   (8 h-dims = 2 b128, L0 x = 4 dims = 1 b128). Each lane: partials for
//   BOTH units x 4 gates (FMA count conserved); 3-round DPP butterfly
//   (xor1, xor2, half_mirror) -> full 8-lane sums; lane half o<4 / o>=4
//   finalizes unit 0 / 1 (transcendental count per lane unchanged).
//   LDS reads: 112 -> 28 b128/iter.
// ---------------------------------------------------------------------------
__global__ __launch_bounds__(512, 1) void fused_all(
    const float* __restrict__ x,
    const float* __restrict__ c1w, const float* __restrict__ c1b,
    const float* __restrict__ c2w, const float* __restrict__ c2b,
    const float* __restrict__ w_ih0, const float* __restrict__ w_hh0,
    const float* __restrict__ b_ih0, const float* __restrict__ b_hh0,
    const float* __restrict__ w_ih1, const float* __restrict__ w_hh1,
    const float* __restrict__ b_ih1, const float* __restrict__ b_hh1,
    const float* __restrict__ fc_w, const float* __restrict__ fc_b,
    float* __restrict__ t1g, float* __restrict__ out) {
  __shared__ __align__(16) float featB[512 * 32];   // 64 KB: this batch's feat
  __shared__ float ws1[144];                        // conv1 w [16][3][3]
  __shared__ float bs1[16];
  __shared__ float ws2[1536];                       // conv2 w [32][16][3]
  __shared__ float bs2[32];
  __shared__ __align__(16) float h0s[2][64];        // h0 double buffer
  __shared__ __align__(16) float h1s[2][64];        // h1 double buffer

  const int tid = threadIdx.x;
  const int b = blockIdx.x;

  // ---- conv weights to LDS ----
  if (tid < 144) ws1[tid] = c1w[tid];
  if (tid < 16)  bs1[tid] = c1b[tid];
  for (int i = tid; i < 1536; i += 512) ws2[i] = c2w[i];
  if (tid < 32)  bs2[tid] = c2b[tid];
  __syncthreads();

  // ---- phase 1: conv1 (3->16, k=3, same) + maxpool2, 2 positions/thread ----
  const float* xb = x + (size_t)b * 2048 * 3;
  float* t1b = t1g + (size_t)b * 1024 * 16;
#pragma unroll
  for (int rep = 0; rep < 2; ++rep) {
    const int t2 = rep * 512 + tid;       // pooled position 0..1023
    const int p0 = 2 * t2;
    float xv[4][3];
#pragma unroll
    for (int j = 0; j < 4; ++j) {
      const int p = p0 - 1 + j;
      const bool ok = (p >= 0) && (p < 2048);
#pragma unroll
      for (int c = 0; c < 3; ++c) xv[j][c] = ok ? xb[p * 3 + c] : 0.0f;
    }
    float4 o4[4];
    float* op = (float*)o4;
#pragma unroll
    for (int o = 0; o < 16; ++o) {
      float s0 = bs1[o], s1 = bs1[o];
#pragma unroll
      for (int c = 0; c < 3; ++c) {
#pragma unroll
        for (int k = 0; k < 3; ++k) {
          const float wv = ws1[(o * 3 + c) * 3 + k];
          s0 = fmaf(xv[k][c],     wv, s0);
          s1 = fmaf(xv[k + 1][c], wv, s1);
        }
      }
      op[o] = fmaxf(s0, s1);
    }
    float4* dst = (float4*)(t1b + (size_t)t2 * 16);
    dst[0] = o4[0]; dst[1] = o4[1]; dst[2] = o4[2]; dst[3] = o4[3];
  }
  __syncthreads();   // t1 writes visible block-wide

  // ---- phase 2: conv2 (16->32, k=3, same) + maxpool2, 1 position/thread ----
  {
    const int t2 = tid;                   // pooled position 0..511
    const int p0 = 2 * t2;
    float4 r4[4][4];
    float* r = (float*)r4;                // r[j*16 + c]
#pragma unroll
    for (int j = 0; j < 4; ++j) {
      const int p = p0 - 1 + j;
      if (p >= 0 && p < 1024) {
        const float4* s = (const float4*)(t1b + p * 16);
        r4[j][0] = s[0]; r4[j][1] = s[1]; r4[j][2] = s[2]; r4[j][3] = s[3];
      } else {
        const float4 z = {0.f, 0.f, 0.f, 0.f};
        r4[j][0] = z; r4[j][1] = z; r4[j][2] = z; r4[j][3] = z;
      }
    }
    float4* dst = (float4*)(featB + (size_t)t2 * 32);
#pragma unroll 4
    for (int o = 0; o < 32; ++o) {
      float s0 = bs2[o], s1 = bs2[o];
      const float* wo = &ws2[o * 48];
#pragma unroll
      for (int c = 0; c < 16; ++c) {
        const float w0 = wo[c * 3], w1 = wo[c * 3 + 1], w2 = wo[c * 3 + 2];
        s0 = fmaf(r[0 * 16 + c], w0, s0);
        s0 = fmaf(r[1 * 16 + c], w1, s0);
        s0 = fmaf(r[2 * 16 + c], w2, s0);
        s1 = fmaf(r[1 * 16 + c], w0, s1);
        s1 = fmaf(r[2 * 16 + c], w1, s1);
        s1 = fmaf(r[3 * 16 + c], w2, s1);
      }
      ((float*)dst)[o] = fmaxf(s0, s1);
    }
  }

  // ---- phase 3: LSTM weight load (8-lane/2-unit layout) ----
  const int layer = tid >> 8;   // 0 or 1 (wave-uniform)
  const int lt  = tid & 255;
  const int g = lt >> 3;        // group 0..31, owns units 2g and 2g+1
  const int o = lt & 7;         // dim-octant
  const int m_own = o >> 2;     // which unit this lane finalizes (0 or 1)

  // a* = unit 2g, b* = unit 2g+1.
  // L0: wx?[j*2+k] (4 x-dims as 2 f2), wh?[j*4+k] (8 h-dims as 4 f2)
  // L1: wx?[j*4+k] (8 dims), wh?[j*4+k] (8 dims)
  f2 wxa[16], wxb[16], wha[16], whb[16];
  float bs4[4];
  if (layer == 0) {
#pragma unroll
    for (int j = 0; j < 4; ++j) {
      {
        const int rrow = j * 64 + 2 * g;
        const float4 px = *(const float4*)(w_ih0 + (size_t)rrow * 32 + o * 4);
        wxa[j * 2 + 0] = (f2){px.x, px.y};
        wxa[j * 2 + 1] = (f2){px.z, px.w};
        const float4* ph = (const float4*)(w_hh0 + (size_t)rrow * 64 + o * 8);
        ld4(&ph[0], wha[j * 4 + 0], wha[j * 4 + 1]);
        ld4(&ph[1], wha[j * 4 + 2], wha[j * 4 + 3]);
      }
      {
        const int rrow = j * 64 + 2 * g + 1;
        const float4 px = *(const float4*)(w_ih0 + (size_t)rrow * 32 + o * 4);
        wxb[j * 2 + 0] = (f2){px.x, px.y};
        wxb[j * 2 + 1] = (f2){px.z, px.w};
        const float4* ph = (const float4*)(w_hh0 + (size_t)rrow * 64 + o * 8);
        ld4(&ph[0], whb[j * 4 + 0], whb[j * 4 + 1]);
        ld4(&ph[1], whb[j * 4 + 2], whb[j * 4 + 3]);
      }
      const int uo = j * 64 + 2 * g + m_own;
      bs4[j] = b_ih0[uo] + b_hh0[uo];
    }
  } else {
#pragma unroll
    for (int j = 0; j < 4; ++j) {
      {
        const int rrow = j * 64 + 2 * g;
        const float4* px = (const float4*)(w_ih1 + (size_t)rrow * 64 + o * 8);
        ld4(&px[0], wxa[j * 4 + 0], wxa[j * 4 + 1]);
        ld4(&px[1], wxa[j * 4 + 2], wxa[j * 4 + 3]);
        const float4* ph = (const float4*)(w_hh1 + (size_t)rrow * 64 + o * 8);
        ld4(&ph[0], wha[j * 4 + 0], wha[j * 4 + 1]);
        ld4(&ph[1], wha[j * 4 + 2], wha[j * 4 + 3]);
      }
      {
        const int rrow = j * 64 + 2 * g + 1;
        const float4* px = (const float4*)(w_ih1 + (size_t)rrow * 64 + o * 8);
        ld4(&px[0], wxb[j * 4 + 0], wxb[j * 4 + 1]);
        ld4(&px[1], wxb[j * 4 + 2], wxb[j * 4 + 3]);
        const float4* ph = (const float4*)(w_hh1 + (size_t)rrow * 64 + o * 8);
        ld4(&ph[0], whb[j * 4 + 0], whb[j * 4 + 1]);
        ld4(&ph[1], whb[j * 4 + 2], whb[j * 4 + 3]);
      }
      const int uo = j * 64 + 2 * g + m_own;
      bs4[j] = b_ih1[uo] + b_hh1[uo];
    }
  }

  // zero h state (buffers read at t=0 / t=1 must be zero; zero all)
  if (tid < 64) {
    h0s[0][tid] = 0.0f; h0s[1][tid] = 0.0f;
    h1s[0][tid] = 0.0f; h1s[1][tid] = 0.0f;
  }

  // featB (phase 2) + h zeroing must be visible BEFORE the t=0 prefetch
  __syncthreads();

  float cc = 0.0f;   // cell state for this lane's own unit (4-lane redundant)

  // ---- phase 4: recurrence, 513 iters, ONE barrier per iter ----
  for (int t = 0; t <= TSTEPS; ++t) {
    // prefetch layer-0 x fragment (featB immutable during loop)
    f2 xpa, xpb;
    if (layer == 0 && t < TSTEPS) {
      const float4 xt = *(const float4*)(featB + t * 32 + o * 4);
      xpa = (f2){xt.x, xt.y};
      xpb = (f2){xt.z, xt.w};
    }
    __syncthreads();   // h[t-1] writes visible

    const bool active = layer ? (t >= 1) : (t < TSTEPS);
    if (active) {
      f2 sa0 = {0.f,0.f}, sa1 = {0.f,0.f}, sa2 = {0.f,0.f}, sa3 = {0.f,0.f};
      f2 sb0 = {0.f,0.f}, sb1 = {0.f,0.f}, sb2 = {0.f,0.f}, sb3 = {0.f,0.f};
      if (layer == 0) {
        // x-part: 4 of 32 input dims (prefetched)
        DOT2(sa0, wxa, 0, xpa, xpb) DOT2(sa1, wxa, 1, xpa, xpb)
        DOT2(sa2, wxa, 2, xpa, xpb) DOT2(sa3, wxa, 3, xpa, xpb)
        DOT2(sb0, wxb, 0, xpa, xpb) DOT2(sb1, wxb, 1, xpa, xpb)
        DOT2(sb2, wxb, 2, xpa, xpb) DOT2(sb3, wxb, 3, xpa, xpb)
        // h-part: this lane's 8 of 64 h0[t-1] dims (2 x b128)
        const float4* hp = (const float4*)(h0s[(t + 1) & 1] + o * 8);
        f2 hv0, hv1, hv2, hv3;
        ld4(&hp[0], hv0, hv1);
        ld4(&hp[1], hv2, hv3);
        DOT4(sa0, wha, 0, hv0, hv1, hv2, hv3) DOT4(sa1, wha, 1, hv0, hv1, hv2, hv3)
        DOT4(sa2, wha, 2, hv0, hv1, hv2, hv3) DOT4(sa3, wha, 3, hv0, hv1, hv2, hv3)
        DOT4(sb0, whb, 0, hv0, hv1, hv2, hv3) DOT4(sb1, whb, 1, hv0, hv1, hv2, hv3)
        DOT4(sb2, whb, 2, hv0, hv1, hv2, hv3) DOT4(sb3, whb, 3, hv0, hv1, hv2, hv3)
      } else {
        // x-part: layer1 input = h0[t-1], this lane's 8 dims (2 x b128)
        const float4* xp = (const float4*)(h0s[(t + 1) & 1] + o * 8);
        f2 xv0, xv1, xv2, xv3;
        ld4(&xp[0], xv0, xv1);
        ld4(&xp[1], xv2, xv3);
        DOT4(sa0, wxa, 0, xv0, xv1, xv2, xv3) DOT4(sa1, wxa, 1, xv0, xv1, xv2, xv3)
        DOT4(sa2, wxa, 2, xv0, xv1, xv2, xv3) DOT4(sa3, wxa, 3, xv0, xv1, xv2, xv3)
        DOT4(sb0, wxb, 0, xv0, xv1, xv2, xv3) DOT4(sb1, wxb, 1, xv0, xv1, xv2, xv3)
        DOT4(sb2, wxb, 2, xv0, xv1, xv2, xv3) DOT4(sb3, wxb, 3, xv0, xv1, xv2, xv3)
        // h-part: h1[t-2], this lane's 8 dims (2 x b128)
        const float4* hp = (const float4*)(h1s[t & 1] + o * 8);
        f2 hv0, hv1, hv2, hv3;
        ld4(&hp[0], hv0, hv1);
        ld4(&hp[1], hv2, hv3);
        DOT4(sa0, wha, 0, hv0, hv1, hv2, hv3) DOT4(sa1, wha, 1, hv0, hv1, hv2, hv3)
        DOT4(sa2, wha, 2, hv0, hv1, hv2, hv3) DOT4(sa3, wha, 3, hv0, hv1, hv2, hv3)
        DOT4(sb0, whb, 0, hv0, hv1, hv2, hv3) DOT4(sb1, whb, 1, hv0, hv1, hv2, hv3)
        DOT4(sb2, whb, 2, hv0, hv1, hv2, hv3) DOT4(sb3, whb, 3, hv0, hv1, hv2, hv3)
      }

      // horizontal add, then 3-round 8-lane butterfly per gate x unit
      float a0 = sa0.x + sa0.y, a1 = sa1.x + sa1.y;
      float a2 = sa2.x + sa2.y, a3 = sa3.x + sa3.y;
      float b0 = sb0.x + sb0.y, b1 = sb1.x + sb1.y;
      float b2 = sb2.x + sb2.y, b3 = sb3.x + sb3.y;
      DPP_ADD(a0, 0xB1);  DPP_ADD(a1, 0xB1);  DPP_ADD(a2, 0xB1);  DPP_ADD(a3, 0xB1);
      DPP_ADD(b0, 0xB1);  DPP_ADD(b1, 0xB1);  DPP_ADD(b2, 0xB1);  DPP_ADD(b3, 0xB1);
      DPP_ADD(a0, 0x4E);  DPP_ADD(a1, 0x4E);  DPP_ADD(a2, 0x4E);  DPP_ADD(a3, 0x4E);
      DPP_ADD(b0, 0x4E);  DPP_ADD(b1, 0x4E);  DPP_ADD(b2, 0x4E);  DPP_ADD(b3, 0x4E);
      DPP_ADD(a0, 0x141); DPP_ADD(a1, 0x141); DPP_ADD(a2, 0x141); DPP_ADD(a3, 0x141);
      DPP_ADD(b0, 0x141); DPP_ADD(b1, 0x141); DPP_ADD(b2, 0x141); DPP_ADD(b3, 0x141);

      // finalize this lane's own unit (lanes o<4 -> unit 2g, o>=4 -> 2g+1)
      const float p0 = (m_own ? b0 : a0) + bs4[0];
      const float p1 = (m_own ? b1 : a1) + bs4[1];
      const float p2 = (m_own ? b2 : a2) + bs4[2];
      const float p3 = (m_own ? b3 : a3) + bs4[3];
      const float ii = sigm(p0), ff = sigm(p1);
      const float gg = tanhf_(p2), oo = sigm(p3);
      cc = fmaf(ff, cc, ii * gg);
      const float hnew = oo * tanhf_(cc);
      if ((o & 3) == 0) {   // lanes o=0 and o=4 write their units
        if (layer == 0) h0s[t & 1][2 * g + m_own] = hnew;          // h0[t]
        else            h1s[(t + 1) & 1][2 * g + m_own] = hnew;    // h1[t-1]
      }
    }
  }
  __syncthreads();

  // fc epilogue: out[b, 0..4] from h1[T-1] (written at iter T into h1s[(T+1)&1])
  if (tid < 5) {
    const float* h = h1s[(TSTEPS + 1) & 1];
    float s = fc_b[tid];
    const float* wrow = fc_w + tid * HID;
#pragma unroll
    for (int j = 0; j < HID; ++j) s = fmaf(wrow[j], h[j], s);
    out[b * 5 + tid] = s;
  }
}

// ---------------------------------------------------------------------------
extern "C" void kernel_launch(void* const* d_in, const int* in_sizes, int n_in,
                              void* d_out, int out_size, void* d_ws, size_t ws_size,
                              hipStream_t stream) {
  (void)in_sizes; (void)n_in; (void)out_size; (void)ws_size;
  const float* x    = (const float*)d_in[0];
  const float* c1w  = (const float*)d_in[1];
  const float* c1b  = (const float*)d_in[2];
  const float* c2w  = (const float*)d_in[3];
  const float* c2b  = (const float*)d_in[4];
  const float* wih0 = (const float*)d_in[5];
  const float* whh0 = (const float*)d_in[6];
  const float* bih0 = (const float*)d_in[7];
  const float* bhh0 = (const float*)d_in[8];
  const float* wih1 = (const float*)d_in[9];
  const float* whh1 = (const float*)d_in[10];
  const float* bih1 = (const float*)d_in[11];
  const float* bhh1 = (const float*)d_in[12];
  const float* fcw  = (const float*)d_in[13];
  const float* fcb  = (const float*)d_in[14];
  float* out = (float*)d_out;

  float* t1 = (float*)d_ws;    // [256,1024,16] = 16 MB (L2-resident per block)

  fused_all<<<256, 512, 0, stream>>>(x, c1w, c1b, c2w, c2b,
                                     wih0, whh0, bih0, bhh0,
                                     wih1, whh1, bih1, bhh1,
                                     fcw, fcb, t1, out);
}

// Round 10
// 506.285 us; speedup vs baseline: 1.0951x; 1.0951x over previous
//
#include <hip/hip_runtime.h>

#define TSTEPS 512   // LSTM sequence length (2048/4)
#define HID    64

typedef float f2 __attribute__((ext_vector_type(2)));

__device__ __forceinline__ float sigm(float x) {
  return 1.0f / (1.0f + __expf(-x));
}
__device__ __forceinline__ float tanhf_(float x) {
  // tanh(x) = 1 - 2/(exp(2x)+1); exact at +-inf, fine vs 5e-3 threshold
  return 1.0f - 2.0f / (1.0f + __expf(2.0f * x));
}

// quad-lane butterfly add via DPP quad_perm (VALU-only, no LDS pipe)
#define DPP_ADD(x, ctrl)                                                       \
  x += __int_as_float(                                                         \
      __builtin_amdgcn_mov_dpp(__float_as_int(x), (ctrl), 0xf, 0xf, true))

// packed fp32 fma -> v_pk_fma_f32 on gfx950
#define PKFMA(acc, w, v) acc = __builtin_elementwise_fma((w), (v), (acc))

// load a float4 from real memory (global/LDS) and split into two f2
__device__ __forceinline__ void ld4(const float4* p, f2& a, f2& b) {
  const float4 t = *p;
  a = (f2){t.x, t.y};
  b = (f2){t.z, t.w};
}

// ---------------------------------------------------------------------------
// ONE kernel: conv1+pool -> t1 (global, L2-resident), conv2+pool -> featB
// (LDS-resident), 2-layer pipelined LSTM recurrence + fc.
// One block per batch element: 256 blocks x 512 threads (1 block/CU).
//
// v10 = v7 (best measured: quad-split gates + DPP butterfly + 1 barrier/iter
//       + v_pk_fma) with two certain fixes:
//   - phase-2 featB writes as float4 (scalar writes were a 64-way bank
//     conflict: all lanes hit bank o at stride-128B rows -> 917K conflict
//     cycles one-time)
//   - ds_read of h issued BEFORE the FMA bodies (explicit load-early)
// ---------------------------------------------------------------------------
__global__ __launch_bounds__(512, 1) void fused_all(
    const float* __restrict__ x,
    const float* __restrict__ c1w, const float* __restrict__ c1b,
    const float* __restrict__ c2w, const float* __restrict__ c2b,
    const float* __restrict__ w_ih0, const float* __restrict__ w_hh0,
    const float* __restrict__ b_ih0, const float* __restrict__ b_hh0,
    const float* __restrict__ w_ih1, const float* __restrict__ w_hh1,
    const float* __restrict__ b_ih1, const float* __restrict__ b_hh1,
    const float* __restrict__ fc_w, const float* __restrict__ fc_b,
    float* __restrict__ t1g, float* __restrict__ out) {
  __shared__ __align__(16) float featB[512 * 32];   // 64 KB: this batch's feat
  __shared__ float ws1[144];                        // conv1 w [16][3][3]
  __shared__ float bs1[16];
  __shared__ float ws2[1536];                       // conv2 w [32][16][3]
  __shared__ float bs2[32];
  __shared__ __align__(16) float h0s[2][64];        // h0 double buffer
  __shared__ __align__(16) float h1s[2][64];        // h1 double buffer

  const int tid = threadIdx.x;
  const int b = blockIdx.x;

  // ---- conv weights to LDS ----
  if (tid < 144) ws1[tid] = c1w[tid];
  if (tid < 16)  bs1[tid] = c1b[tid];
  for (int i = tid; i < 1536; i += 512) ws2[i] = c2w[i];
  if (tid < 32)  bs2[tid] = c2b[tid];
  __syncthreads();

  // ---- phase 1: conv1 (3->16, k=3, same) + maxpool2, 2 positions/thread ----
  const float* xb = x + (size_t)b * 2048 * 3;
  float* t1b = t1g + (size_t)b * 1024 * 16;
#pragma unroll
  for (int rep = 0; rep < 2; ++rep) {
    const int t2 = rep * 512 + tid;       // pooled position 0..1023
    const int p0 = 2 * t2;
    float xv[4][3];
#pragma unroll
    for (int j = 0; j < 4; ++j) {
      const int p = p0 - 1 + j;
      const bool ok = (p >= 0) && (p < 2048);
#pragma unroll
      for (int c = 0; c < 3; ++c) xv[j][c] = ok ? xb[p * 3 + c] : 0.0f;
    }
    float4 o4[4];
    float* op = (float*)o4;
#pragma unroll
    for (int o = 0; o < 16; ++o) {
      float s0 = bs1[o], s1 = bs1[o];
#pragma unroll
      for (int c = 0; c < 3; ++c) {
#pragma unroll
        for (int k = 0; k < 3; ++k) {
          const float wv = ws1[(o * 3 + c) * 3 + k];
          s0 = fmaf(xv[k][c],     wv, s0);
          s1 = fmaf(xv[k + 1][c], wv, s1);
        }
      }
      op[o] = fmaxf(s0, s1);
    }
    float4* dst = (float4*)(t1b + (size_t)t2 * 16);
    dst[0] = o4[0]; dst[1] = o4[1]; dst[2] = o4[2]; dst[3] = o4[3];
  }
  __syncthreads();   // t1 writes visible block-wide

  // ---- phase 2: conv2 (16->32, k=3, same) + maxpool2, 1 position/thread ----
  {
    const int t2 = tid;                   // pooled position 0..511
    const int p0 = 2 * t2;
    float4 r4[4][4];
    float* r = (float*)r4;                // r[j*16 + c]
#pragma unroll
    for (int j = 0; j < 4; ++j) {
      const int p = p0 - 1 + j;
      if (p >= 0 && p < 1024) {
        const float4* s = (const float4*)(t1b + p * 16);
        r4[j][0] = s[0]; r4[j][1] = s[1]; r4[j][2] = s[2]; r4[j][3] = s[3];
      } else {
        const float4 z = {0.f, 0.f, 0.f, 0.f};
        r4[j][0] = z; r4[j][1] = z; r4[j][2] = z; r4[j][3] = z;
      }
    }
    float4 o4[8];
    float* op = (float*)o4;
#pragma unroll 4
    for (int o = 0; o < 32; ++o) {
      float s0 = bs2[o], s1 = bs2[o];
      const float* wo = &ws2[o * 48];
#pragma unroll
      for (int c = 0; c < 16; ++c) {
        const float w0 = wo[c * 3], w1 = wo[c * 3 + 1], w2 = wo[c * 3 + 2];
        s0 = fmaf(r[0 * 16 + c], w0, s0);
        s0 = fmaf(r[1 * 16 + c], w1, s0);
        s0 = fmaf(r[2 * 16 + c], w2, s0);
        s1 = fmaf(r[1 * 16 + c], w0, s1);
        s1 = fmaf(r[2 * 16 + c], w1, s1);
        s1 = fmaf(r[3 * 16 + c], w2, s1);
      }
      op[o] = fmaxf(s0, s1);
    }
    // float4 writes: 16-way instead of 64-way bank conflict
    float4* dst = (float4*)(featB + (size_t)t2 * 32);
#pragma unroll
    for (int qq = 0; qq < 8; ++qq) dst[qq] = o4[qq];
  }

  // ---- phase 3: LSTM weight load (quad-split layout, as v4) ----
  const int layer = tid >> 8;   // 0 or 1 (wave-uniform)
  const int lt  = tid & 255;
  const int u = lt >> 2;        // unit 0..63
  const int q = lt & 3;         // dim-quarter / quad slot

  // L0: wx[g*4+dd] dd<4 (8 x-dims), wh[g*8+dd] dd<8 (16 h-dims)
  // L1: wx[g*8+dd] dd<8 (16 dims),  wh[g*8+dd] dd<8 (16 dims)
  f2 wx[32], wh[32];
  float bs4[4];
  if (layer == 0) {
#pragma unroll
    for (int j = 0; j < 4; ++j) {
      const int rrow = j * 64 + u;
      const float4* px = (const float4*)(w_ih0 + (size_t)rrow * 32 + q * 8);
      ld4(&px[0], wx[j * 4 + 0], wx[j * 4 + 1]);
      ld4(&px[1], wx[j * 4 + 2], wx[j * 4 + 3]);
      const float4* ph = (const float4*)(w_hh0 + (size_t)rrow * 64 + q * 16);
#pragma unroll
      for (int k = 0; k < 4; ++k)
        ld4(&ph[k], wh[j * 8 + 2 * k], wh[j * 8 + 2 * k + 1]);
      bs4[j] = b_ih0[rrow] + b_hh0[rrow];
    }
  } else {
#pragma unroll
    for (int j = 0; j < 4; ++j) {
      const int rrow = j * 64 + u;
      const float4* px = (const float4*)(w_ih1 + (size_t)rrow * 64 + q * 16);
#pragma unroll
      for (int k = 0; k < 4; ++k)
        ld4(&px[k], wx[j * 8 + 2 * k], wx[j * 8 + 2 * k + 1]);
      const float4* ph = (const float4*)(w_hh1 + (size_t)rrow * 64 + q * 16);
#pragma unroll
      for (int k = 0; k < 4; ++k)
        ld4(&ph[k], wh[j * 8 + 2 * k], wh[j * 8 + 2 * k + 1]);
      bs4[j] = b_ih1[rrow] + b_hh1[rrow];
    }
  }

  // zero h state (buffers read at t=0 / t=1 must be zero; zero all)
  if (tid < 64) {
    h0s[0][tid] = 0.0f; h0s[1][tid] = 0.0f;
    h1s[0][tid] = 0.0f; h1s[1][tid] = 0.0f;
  }

  // featB (phase 2) + h zeroing must be visible BEFORE the t=0 prefetch
  __syncthreads();

  float cc = 0.0f;   // cell state, kept redundantly in all 4 lanes of a quad

  // ---- phase 4: recurrence, 513 iters, ONE barrier per iter ----
  for (int t = 0; t <= TSTEPS; ++t) {
    // prefetch layer-0 x fragment (featB immutable during loop)
    f2 xv0, xv1, xv2, xv3;
    if (layer == 0 && t < TSTEPS) {
      const float4* xt = (const float4*)(featB + t * 32 + q * 8);
      ld4(&xt[0], xv0, xv1);
      ld4(&xt[1], xv2, xv3);
    }
    __syncthreads();   // h[t-1] writes visible

    const bool active = layer ? (t >= 1) : (t < TSTEPS);
    if (active) {
      f2 s0 = {0.f, 0.f}, s1 = {0.f, 0.f}, s2 = {0.f, 0.f}, s3 = {0.f, 0.f};
      if (layer == 0) {
        // issue h-read FIRST (latency hides under the x-part FMAs below)
        const float4* hp = (const float4*)(h0s[(t + 1) & 1] + q * 16);
        f2 hv[8];
#pragma unroll
        for (int k = 0; k < 4; ++k) ld4(&hp[k], hv[2 * k], hv[2 * k + 1]);
        // x-part: prefetched 8 of 32 input dims (4 packed pairs)
        PKFMA(s0, wx[0],  xv0); PKFMA(s0, wx[1],  xv1);
        PKFMA(s0, wx[2],  xv2); PKFMA(s0, wx[3],  xv3);
        PKFMA(s1, wx[4],  xv0); PKFMA(s1, wx[5],  xv1);
        PKFMA(s1, wx[6],  xv2); PKFMA(s1, wx[7],  xv3);
        PKFMA(s2, wx[8],  xv0); PKFMA(s2, wx[9],  xv1);
        PKFMA(s2, wx[10], xv2); PKFMA(s2, wx[11], xv3);
        PKFMA(s3, wx[12], xv0); PKFMA(s3, wx[13], xv1);
        PKFMA(s3, wx[14], xv2); PKFMA(s3, wx[15], xv3);
        // h-part: this lane's 16 of 64 h0[t-1] dims (8 packed pairs)
#pragma unroll
        for (int dd = 0; dd < 8; ++dd) {
          PKFMA(s0, wh[dd],      hv[dd]);
          PKFMA(s1, wh[8 + dd],  hv[dd]);
          PKFMA(s2, wh[16 + dd], hv[dd]);
          PKFMA(s3, wh[24 + dd], hv[dd]);
        }
      } else {
        // issue both reads FIRST
        const float4* xp = (const float4*)(h0s[(t + 1) & 1] + q * 16);
        f2 xv[8];
#pragma unroll
        for (int k = 0; k < 4; ++k) ld4(&xp[k], xv[2 * k], xv[2 * k + 1]);
        const float4* hp = (const float4*)(h1s[t & 1] + q * 16);
        f2 hv[8];
#pragma unroll
        for (int k = 0; k < 4; ++k) ld4(&hp[k], hv[2 * k], hv[2 * k + 1]);
        // x-part: layer1 input = h0[t-1], this lane's 16 dims
#pragma unroll
        for (int dd = 0; dd < 8; ++dd) {
          PKFMA(s0, wx[dd],      xv[dd]);
          PKFMA(s1, wx[8 + dd],  xv[dd]);
          PKFMA(s2, wx[16 + dd], xv[dd]);
          PKFMA(s3, wx[24 + dd], xv[dd]);
        }
        // h-part: h1[t-2], this lane's 16 dims
#pragma unroll
        for (int dd = 0; dd < 8; ++dd) {
          PKFMA(s0, wh[dd],      hv[dd]);
          PKFMA(s1, wh[8 + dd],  hv[dd]);
          PKFMA(s2, wh[16 + dd], hv[dd]);
          PKFMA(s3, wh[24 + dd], hv[dd]);
        }
      }

      // in-lane horizontal add, then quad butterfly over the 4 dim-quarters
      float a0 = s0.x + s0.y, a1 = s1.x + s1.y;
      float a2 = s2.x + s2.y, a3 = s3.x + s3.y;
      // quad_perm [1,0,3,2] = 0xB1 (xor 1), [2,3,0,1] = 0x4E (xor 2)
      DPP_ADD(a0, 0xB1); DPP_ADD(a1, 0xB1); DPP_ADD(a2, 0xB1); DPP_ADD(a3, 0xB1);
      DPP_ADD(a0, 0x4E); DPP_ADD(a1, 0x4E); DPP_ADD(a2, 0x4E); DPP_ADD(a3, 0x4E);

      // in-quad update (all 4 lanes redundantly; bias added post-reduce)
      const float pi = a0 + bs4[0], pf = a1 + bs4[1];
      const float pg = a2 + bs4[2], po = a3 + bs4[3];
      const float ii = sigm(pi), ff = sigm(pf);
      const float gg = tanhf_(pg), oo = sigm(po);
      cc = fmaf(ff, cc, ii * gg);
      const float hnew = oo * tanhf_(cc);
      if (q == 0) {
        if (layer == 0) h0s[t & 1][u] = hnew;          // h0[t]
        else            h1s[(t + 1) & 1][u] = hnew;    // h1[t-1]
      }
    }
  }
  __syncthreads();

  // fc epilogue: out[b, 0..4] from h1[T-1] (written at iter T into h1s[(T+1)&1])
  if (tid < 5) {
    const float* h = h1s[(TSTEPS + 1) & 1];
    float s = fc_b[tid];
    const float* wrow = fc_w + tid * HID;
#pragma unroll
    for (int j = 0; j < HID; ++j) s = fmaf(wrow[j], h[j], s);
    out[b * 5 + tid] = s;
  }
}

// ---------------------------------------------------------------------------
extern "C" void kernel_launch(void* const* d_in, const int* in_sizes, int n_in,
                              void* d_out, int out_size, void* d_ws, size_t ws_size,
                              hipStream_t stream) {
  (void)in_sizes; (void)n_in; (void)out_size; (void)ws_size;
  const float* x    = (const float*)d_in[0];
  const float* c1w  = (const float*)d_in[1];
  const float* c1b  = (const float*)d_in[2];
  const float* c2w  = (const float*)d_in[3];
  const float* c2b  = (const float*)d_in[4];
  const float* wih0 = (const float*)d_in[5];
  const float* whh0 = (const float*)d_in[6];
  const float* bih0 = (const float*)d_in[7];
  const float* bhh0 = (const float*)d_in[8];
  const float* wih1 = (const float*)d_in[9];
  const float* whh1 = (const float*)d_in[10];
  const float* bih1 = (const float*)d_in[11];
  const float* bhh1 = (const float*)d_in[12];
  const float* fcw  = (const float*)d_in[13];
  const float* fcb  = (const float*)d_in[14];
  float* out = (float*)d_out;

  float* t1 = (float*)d_ws;    // [256,1024,16] = 16 MB (L2-resident per block)

  fused_all<<<256, 512, 0, stream>>>(x, c1w, c1b, c2w, c2b,
                                     wih0, whh0, bih0, bhh0,
                                     wih1, whh1, bih1, bhh1,
                                     fcw, fcb, t1, out);
}

// Round 11
// 401.814 us; speedup vs baseline: 1.3799x; 1.2600x over previous
//
#include <hip/hip_runtime.h>

#define TSTEPS 512   // LSTM sequence length (2048/4)
#define HID    64

typedef float f2 __attribute__((ext_vector_type(2)));

// raw 2^x / 1/x (1-instr, ~1ulp; fine vs 5e-3 threshold)
#if __has_builtin(__builtin_amdgcn_exp2f)
#define EXP2F(x) __builtin_amdgcn_exp2f(x)
#else
#define EXP2F(x) exp2f(x)
#endif
#if __has_builtin(__builtin_amdgcn_rcpf)
#define RCPF(x) __builtin_amdgcn_rcpf(x)
#else
#define RCPF(x) (1.0f / (x))
#endif

#define CL   1.4426950408889634f   // log2(e)
#define C2L  2.8853900817779268f   // 2*log2(e)
#define C4L  5.7707801635558536f   // 4*log2(e)

// quad-lane butterfly add via DPP quad_perm (VALU-only, no LDS pipe)
#define DPP_ADD(x, ctrl)                                                       \
  x += __int_as_float(                                                         \
      __builtin_amdgcn_mov_dpp(__float_as_int(x), (ctrl), 0xf, 0xf, true))

// packed fp32 fma -> v_pk_fma_f32 on gfx950
#define PKFMA(acc, w, v) acc = __builtin_elementwise_fma((w), (v), (acc))

// load a float4 from real memory (global/LDS) and split into two f2
__device__ __forceinline__ void ld4(const float4* p, f2& a, f2& b) {
  const float4 t = *p;
  a = (f2){t.x, t.y};
  b = (f2){t.z, t.w};
}

// ---------------------------------------------------------------------------
// ONE kernel: conv1+pool -> t1 (global, L2-resident), conv2+pool -> featB
// (LDS-resident), 2-layer pipelined LSTM recurrence + fc.
// One block per batch element: 256 blocks x 512 threads (1 block/CU).
//
// v11 = v7 (best measured, 476us dispatch) + serial-tail diet:
//   - v_rcp_f32 replaces the 5 IEEE divides in sigm/tanh (~8-10 instr each,
//     all on the post-reduce serial critical path)
//   - exp2-domain pre-scaling: gate weights & biases scaled by log2e
//     (g-gate by 2*log2e) at LOAD; cell state kept scaled by 2*log2e
//     -> raw exp2, no input muls anywhere in the activation chain
//   - bias folded into the q==0 lane's accumulator init (pre-reduce,
//     outside the tail)
//   Phase-2 writes reverted to direct scalar stores (R10's o4/op punning
//   caused 16 MB of scratch traffic; the 917K bank-conflict count is
//   unrelated and benign at 0.3%).
// ---------------------------------------------------------------------------
__global__ __launch_bounds__(512, 1) void fused_all(
    const float* __restrict__ x,
    const float* __restrict__ c1w, const float* __restrict__ c1b,
    const float* __restrict__ c2w, const float* __restrict__ c2b,
    const float* __restrict__ w_ih0, const float* __restrict__ w_hh0,
    const float* __restrict__ b_ih0, const float* __restrict__ b_hh0,
    const float* __restrict__ w_ih1, const float* __restrict__ w_hh1,
    const float* __restrict__ b_ih1, const float* __restrict__ b_hh1,
    const float* __restrict__ fc_w, const float* __restrict__ fc_b,
    float* __restrict__ t1g, float* __restrict__ out) {
  __shared__ __align__(16) float featB[512 * 32];   // 64 KB: this batch's feat
  __shared__ float ws1[144];                        // conv1 w [16][3][3]
  __shared__ float bs1[16];
  __shared__ float ws2[1536];                       // conv2 w [32][16][3]
  __shared__ float bs2[32];
  __shared__ __align__(16) float h0s[2][64];        // h0 double buffer
  __shared__ __align__(16) float h1s[2][64];        // h1 double buffer

  const int tid = threadIdx.x;
  const int b = blockIdx.x;

  // ---- conv weights to LDS ----
  if (tid < 144) ws1[tid] = c1w[tid];
  if (tid < 16)  bs1[tid] = c1b[tid];
  for (int i = tid; i < 1536; i += 512) ws2[i] = c2w[i];
  if (tid < 32)  bs2[tid] = c2b[tid];
  __syncthreads();

  // ---- phase 1: conv1 (3->16, k=3, same) + maxpool2, 2 positions/thread ----
  const float* xb = x + (size_t)b * 2048 * 3;
  float* t1b = t1g + (size_t)b * 1024 * 16;
#pragma unroll
  for (int rep = 0; rep < 2; ++rep) {
    const int t2 = rep * 512 + tid;       // pooled position 0..1023
    const int p0 = 2 * t2;
    float xv[4][3];
#pragma unroll
    for (int j = 0; j < 4; ++j) {
      const int p = p0 - 1 + j;
      const bool ok = (p >= 0) && (p < 2048);
#pragma unroll
      for (int c = 0; c < 3; ++c) xv[j][c] = ok ? xb[p * 3 + c] : 0.0f;
    }
    float4 o4[4];
    float* op = (float*)o4;
#pragma unroll
    for (int o = 0; o < 16; ++o) {
      float s0 = bs1[o], s1 = bs1[o];
#pragma unroll
      for (int c = 0; c < 3; ++c) {
#pragma unroll
        for (int k = 0; k < 3; ++k) {
          const float wv = ws1[(o * 3 + c) * 3 + k];
          s0 = fmaf(xv[k][c],     wv, s0);
          s1 = fmaf(xv[k + 1][c], wv, s1);
        }
      }
      op[o] = fmaxf(s0, s1);
    }
    float4* dst = (float4*)(t1b + (size_t)t2 * 16);
    dst[0] = o4[0]; dst[1] = o4[1]; dst[2] = o4[2]; dst[3] = o4[3];
  }
  __syncthreads();   // t1 writes visible block-wide

  // ---- phase 2: conv2 (16->32, k=3, same) + maxpool2, 1 position/thread ----
  {
    const int t2 = tid;                   // pooled position 0..511
    const int p0 = 2 * t2;
    float4 r4[4][4];
    float* r = (float*)r4;                // r[j*16 + c]
#pragma unroll
    for (int j = 0; j < 4; ++j) {
      const int p = p0 - 1 + j;
      if (p >= 0 && p < 1024) {
        const float4* s = (const float4*)(t1b + p * 16);
        r4[j][0] = s[0]; r4[j][1] = s[1]; r4[j][2] = s[2]; r4[j][3] = s[3];
      } else {
        const float4 z = {0.f, 0.f, 0.f, 0.f};
        r4[j][0] = z; r4[j][1] = z; r4[j][2] = z; r4[j][3] = z;
      }
    }
    float* dst = featB + (size_t)t2 * 32;
#pragma unroll 4
    for (int o = 0; o < 32; ++o) {
      float s0 = bs2[o], s1 = bs2[o];
      const float* wo = &ws2[o * 48];
#pragma unroll
      for (int c = 0; c < 16; ++c) {
        const float w0 = wo[c * 3], w1 = wo[c * 3 + 1], w2 = wo[c * 3 + 2];
        s0 = fmaf(r[0 * 16 + c], w0, s0);
        s0 = fmaf(r[1 * 16 + c], w1, s0);
        s0 = fmaf(r[2 * 16 + c], w2, s0);
        s1 = fmaf(r[1 * 16 + c], w0, s1);
        s1 = fmaf(r[2 * 16 + c], w1, s1);
        s1 = fmaf(r[3 * 16 + c], w2, s1);
      }
      dst[o] = fmaxf(s0, s1);
    }
  }

  // ---- phase 3: LSTM weight load (quad-split layout + exp2 pre-scale) ----
  const int layer = tid >> 8;   // 0 or 1 (wave-uniform)
  const int lt  = tid & 255;
  const int u = lt >> 2;        // unit 0..63
  const int q = lt & 3;         // dim-quarter / quad slot

  // gate j scale: i,f,o -> log2e; g -> 2*log2e (exp2-domain activations)
  // L0: wx[g*4+dd] dd<4 (8 x-dims), wh[g*8+dd] dd<8 (16 h-dims)
  // L1: wx[g*8+dd] dd<8 (16 dims),  wh[g*8+dd] dd<8 (16 dims)
  f2 wx[32], wh[32], bi[4];
  if (layer == 0) {
#pragma unroll
    for (int j = 0; j < 4; ++j) {
      const int rrow = j * 64 + u;
      const float sc = (j == 2) ? C2L : CL;
      const float4* px = (const float4*)(w_ih0 + (size_t)rrow * 32 + q * 8);
      ld4(&px[0], wx[j * 4 + 0], wx[j * 4 + 1]);
      ld4(&px[1], wx[j * 4 + 2], wx[j * 4 + 3]);
      const float4* ph = (const float4*)(w_hh0 + (size_t)rrow * 64 + q * 16);
#pragma unroll
      for (int k = 0; k < 4; ++k)
        ld4(&ph[k], wh[j * 8 + 2 * k], wh[j * 8 + 2 * k + 1]);
#pragma unroll
      for (int k = 0; k < 4; ++k) wx[j * 4 + k] *= sc;
#pragma unroll
      for (int k = 0; k < 8; ++k) wh[j * 8 + k] *= sc;
      const float bsc = (b_ih0[rrow] + b_hh0[rrow]) * sc;
      bi[j] = (q == 0) ? (f2){bsc, 0.f} : (f2){0.f, 0.f};
    }
  } else {
#pragma unroll
    for (int j = 0; j < 4; ++j) {
      const int rrow = j * 64 + u;
      const float sc = (j == 2) ? C2L : CL;
      const float4* px = (const float4*)(w_ih1 + (size_t)rrow * 64 + q * 16);
#pragma unroll
      for (int k = 0; k < 4; ++k)
        ld4(&px[k], wx[j * 8 + 2 * k], wx[j * 8 + 2 * k + 1]);
      const float4* ph = (const float4*)(w_hh1 + (size_t)rrow * 64 + q * 16);
#pragma unroll
      for (int k = 0; k < 4; ++k)
        ld4(&ph[k], wh[j * 8 + 2 * k], wh[j * 8 + 2 * k + 1]);
#pragma unroll
      for (int k = 0; k < 8; ++k) { wx[j * 8 + k] *= sc; wh[j * 8 + k] *= sc; }
      const float bsc = (b_ih1[rrow] + b_hh1[rrow]) * sc;
      bi[j] = (q == 0) ? (f2){bsc, 0.f} : (f2){0.f, 0.f};
    }
  }

  // zero h state (buffers read at t=0 / t=1 must be zero; zero all)
  if (tid < 64) {
    h0s[0][tid] = 0.0f; h0s[1][tid] = 0.0f;
    h1s[0][tid] = 0.0f; h1s[1][tid] = 0.0f;
  }

  // featB (phase 2) + h zeroing must be visible BEFORE the t=0 prefetch
  __syncthreads();

  float cc = 0.0f;   // cell state SCALED by 2*log2e, redundant in quad

  // ---- phase 4: recurrence, 513 iters, ONE barrier per iter ----
  for (int t = 0; t <= TSTEPS; ++t) {
    // prefetch layer-0 x fragment (featB immutable during loop)
    f2 xv0, xv1, xv2, xv3;
    if (layer == 0 && t < TSTEPS) {
      const float4* xt = (const float4*)(featB + t * 32 + q * 8);
      ld4(&xt[0], xv0, xv1);
      ld4(&xt[1], xv2, xv3);
    }
    __syncthreads();   // h[t-1] writes visible

    const bool active = layer ? (t >= 1) : (t < TSTEPS);
    if (active) {
      f2 s0 = bi[0], s1 = bi[1], s2 = bi[2], s3 = bi[3];
      if (layer == 0) {
        // x-part: prefetched 8 of 32 input dims (4 packed pairs)
        PKFMA(s0, wx[0],  xv0); PKFMA(s0, wx[1],  xv1);
        PKFMA(s0, wx[2],  xv2); PKFMA(s0, wx[3],  xv3);
        PKFMA(s1, wx[4],  xv0); PKFMA(s1, wx[5],  xv1);
        PKFMA(s1, wx[6],  xv2); PKFMA(s1, wx[7],  xv3);
        PKFMA(s2, wx[8],  xv0); PKFMA(s2, wx[9],  xv1);
        PKFMA(s2, wx[10], xv2); PKFMA(s2, wx[11], xv3);
        PKFMA(s3, wx[12], xv0); PKFMA(s3, wx[13], xv1);
        PKFMA(s3, wx[14], xv2); PKFMA(s3, wx[15], xv3);
        // h-part: this lane's 16 of 64 h0[t-1] dims (8 packed pairs)
        const float4* hp = (const float4*)(h0s[(t + 1) & 1] + q * 16);
        f2 hv[8];
#pragma unroll
        for (int k = 0; k < 4; ++k) ld4(&hp[k], hv[2 * k], hv[2 * k + 1]);
#pragma unroll
        for (int dd = 0; dd < 8; ++dd) {
          PKFMA(s0, wh[dd],      hv[dd]);
          PKFMA(s1, wh[8 + dd],  hv[dd]);
          PKFMA(s2, wh[16 + dd], hv[dd]);
          PKFMA(s3, wh[24 + dd], hv[dd]);
        }
      } else {
        // x-part: layer1 input = h0[t-1], this lane's 16 dims
        const float4* xp = (const float4*)(h0s[(t + 1) & 1] + q * 16);
        f2 xv[8];
#pragma unroll
        for (int k = 0; k < 4; ++k) ld4(&xp[k], xv[2 * k], xv[2 * k + 1]);
#pragma unroll
        for (int dd = 0; dd < 8; ++dd) {
          PKFMA(s0, wx[dd],      xv[dd]);
          PKFMA(s1, wx[8 + dd],  xv[dd]);
          PKFMA(s2, wx[16 + dd], xv[dd]);
          PKFMA(s3, wx[24 + dd], xv[dd]);
        }
        // h-part: h1[t-2], this lane's 16 dims
        const float4* hp = (const float4*)(h1s[t & 1] + q * 16);
        f2 hv[8];
#pragma unroll
        for (int k = 0; k < 4; ++k) ld4(&hp[k], hv[2 * k], hv[2 * k + 1]);
#pragma unroll
        for (int dd = 0; dd < 8; ++dd) {
          PKFMA(s0, wh[dd],      hv[dd]);
          PKFMA(s1, wh[8 + dd],  hv[dd]);
          PKFMA(s2, wh[16 + dd], hv[dd]);
          PKFMA(s3, wh[24 + dd], hv[dd]);
        }
      }

      // in-lane horizontal add, then quad butterfly over the 4 dim-quarters
      // (bias was folded into lane q==0's accumulator init)
      float a0 = s0.x + s0.y, a1 = s1.x + s1.y;
      float a2 = s2.x + s2.y, a3 = s3.x + s3.y;
      // quad_perm [1,0,3,2] = 0xB1 (xor 1), [2,3,0,1] = 0x4E (xor 2)
      DPP_ADD(a0, 0xB1); DPP_ADD(a1, 0xB1); DPP_ADD(a2, 0xB1); DPP_ADD(a3, 0xB1);
      DPP_ADD(a0, 0x4E); DPP_ADD(a1, 0x4E); DPP_ADD(a2, 0x4E); DPP_ADD(a3, 0x4E);

      // exp2-domain update: a0,a1,a3 = log2e*p(i,f,o); a2 = 2log2e*p(g)
      const float ii = RCPF(1.0f + EXP2F(-a0));                 // sigm(pi)
      const float ff = RCPF(1.0f + EXP2F(-a1));                 // sigm(pf)
      const float gs = fmaf(-C4L, RCPF(1.0f + EXP2F(a2)), C2L); // 2L*tanh(pg)
      const float oo = RCPF(1.0f + EXP2F(-a3));                 // sigm(po)
      cc = fmaf(ff, cc, ii * gs);                               // 2L*c
      const float th = fmaf(-2.0f, RCPF(1.0f + EXP2F(cc)), 1.0f); // tanh(c)
      const float hnew = oo * th;
      if (q == 0) {
        if (layer == 0) h0s[t & 1][u] = hnew;          // h0[t]
        else            h1s[(t + 1) & 1][u] = hnew;    // h1[t-1]
      }
    }
  }
  __syncthreads();

  // fc epilogue: out[b, 0..4] from h1[T-1] (written at iter T into h1s[(T+1)&1])
  if (tid < 5) {
    const float* h = h1s[(TSTEPS + 1) & 1];
    float s = fc_b[tid];
    const float* wrow = fc_w + tid * HID;
#pragma unroll
    for (int j = 0; j < HID; ++j) s = fmaf(wrow[j], h[j], s);
    out[b * 5 + tid] = s;
  }
}

// ---------------------------------------------------------------------------
extern "C" void kernel_launch(void* const* d_in, const int* in_sizes, int n_in,
                              void* d_out, int out_size, void* d_ws, size_t ws_size,
                              hipStream_t stream) {
  (void)in_sizes; (void)n_in; (void)out_size; (void)ws_size;
  const float* x    = (const float*)d_in[0];
  const float* c1w  = (const float*)d_in[1];
  const float* c1b  = (const float*)d_in[2];
  const float* c2w  = (const float*)d_in[3];
  const float* c2b  = (const float*)d_in[4];
  const float* wih0 = (const float*)d_in[5];
  const float* whh0 = (const float*)d_in[6];
  const float* bih0 = (const float*)d_in[7];
  const float* bhh0 = (const float*)d_in[8];
  const float* wih1 = (const float*)d_in[9];
  const float* whh1 = (const float*)d_in[10];
  const float* bih1 = (const float*)d_in[11];
  const float* bhh1 = (const float*)d_in[12];
  const float* fcw  = (const float*)d_in[13];
  const float* fcb  = (const float*)d_in[14];
  float* out = (float*)d_out;

  float* t1 = (float*)d_ws;    // [256,1024,16] = 16 MB (L2-resident per block)

  fused_all<<<256, 512, 0, stream>>>(x, c1w, c1b, c2w, c2b,
                                     wih0, whh0, bih0, bhh0,
                                     wih1, whh1, bih1, bhh1,
                                     fcw, fcb, t1, out);
}